// Round 4
// baseline (129.211 us; speedup 1.0000x reference)
//
#include <hip/hip_runtime.h>

// NoisyTopExpertsPerItemRouter: G=32,S=1024,H=2048,E=64,K=2 (top-2)
// Outputs (concat, f32): idx (N*2) | w (N*2) | aux (1) | probs (N*64)
//
// Split-precision bf16 MFMA GEMM, fully register-resident K-loop:
//   a = ah + 2^-8*amS, w = wh + 2^-8*wmS; logits = accM + 2^-8*accS
//   (dropped terms <= ~2^-16 relative -> f32-grade logits, validated R3)
// W decomposed once by prep_kernel into fragment-linear bf16 arrays in ws;
// router loads A and B fragments global->VGPR, no LDS / barriers in K-loop.

constexpr int GS  = 32768;
constexpr int EXP = 64;
constexpr int HID = 2048;
constexpr int BM  = 64;        // rows per block (4 waves x 16 rows)
constexpr int NCH = HID / 32;  // 64 k-chunks

typedef __attribute__((ext_vector_type(8))) short s16x8;
typedef __attribute__((ext_vector_type(4))) float f32x4;

__device__ __forceinline__ void decomp8(float4 x0, float4 x1, s16x8& h, s16x8& m)
{
    float v[8] = {x0.x,x0.y,x0.z,x0.w,x1.x,x1.y,x1.z,x1.w};
    #pragma unroll
    for (int i = 0; i < 8; ++i) {
        union { float f; unsigned u; } a; a.f = v[i];
        unsigned hb = (a.u + 0x7fffu + ((a.u >> 16) & 1u)) >> 16;  // RNE bf16
        union { unsigned u; float f; } hf; hf.u = hb << 16;
        float r = (v[i] - hf.f) * 256.f;         // exact residual, scaled 2^8
        union { float f; unsigned u; } rb; rb.f = r;
        h[i] = (short)hb;
        m[i] = (short)(rb.u >> 16);              // trunc; total err ~2^-16|v|
    }
}

// W fragments: frag index f = c*256 + nt*64 + lane encodes
//   expert e = nt*16 + (lane&15), k = c*32 + (lane>>4)*8 + j   (j=0..7)
__global__ __launch_bounds__(256)
void prep_kernel(const float* __restrict__ W, short* __restrict__ WhF,
                 short* __restrict__ WmF)
{
    const int t  = blockIdx.x * 256 + threadIdx.x;   // 0..16383
    const int c  = t >> 8;
    const int nt = (t >> 6) & 3;
    const int l  = t & 63;
    const int e  = nt * 16 + (l & 15);
    const int kb = c * 32 + ((l >> 4) << 3);
    const float* p = W + (size_t)e * HID + kb;
    float4 x0 = *(const float4*)p;
    float4 x1 = *(const float4*)(p + 4);
    s16x8 h, m;
    decomp8(x0, x1, h, m);
    *(s16x8*)&WhF[(size_t)t * 8] = h;
    *(s16x8*)&WmF[(size_t)t * 8] = m;
}

__global__ __launch_bounds__(256)
void router_kernel(const float* __restrict__ tokens,
                   const float* __restrict__ noise,
                   const float* __restrict__ bias,
                   const s16x8* __restrict__ WhF,
                   const s16x8* __restrict__ WmF,
                   float* __restrict__ out,
                   float* __restrict__ ws)
{
    __shared__ float lg[BM][EXP + 1];   // wave-private transpose buffer
    __shared__ float red[8][EXP];

    const int tid  = threadIdx.x;
    const int lane = tid & 63;
    const int wv   = tid >> 6;
    const int row0 = blockIdx.x * BM;

    // A fragment source: lane -> row = lane&15 (of this wave's 16 rows),
    // k-slice = (lane>>4)*8 .. +8 within each 32-wide chunk
    const float* Ap = tokens
        + (size_t)(row0 + wv * 16 + (lane & 15)) * HID + ((lane >> 4) << 3);

    f32x4 accM[4], accS[4];
    #pragma unroll
    for (int nt = 0; nt < 4; ++nt) { accM[nt] = (f32x4)0.f; accS[nt] = (f32x4)0.f; }

    // 2-bank register double buffer (named banks: all indices compile-time)
    float4 aA0, aA1, aB0, aB1;
    s16x8 whA[4], wmA[4], whB[4], wmB[4];

    aA0 = *(const float4*)(Ap);
    aA1 = *(const float4*)(Ap + 4);
    #pragma unroll
    for (int nt = 0; nt < 4; ++nt) {
        whA[nt] = WhF[nt * 64 + lane];
        wmA[nt] = WmF[nt * 64 + lane];
    }

#define ROUTER_STEP(A0, A1, WH, WM, N0, N1, NWH, NWM, c)                          \
    {                                                                              \
        if ((c) + 1 < NCH) {  /* issue next chunk's loads before compute */        \
            N0 = *(const float4*)(Ap + ((c) + 1) * 32);                            \
            N1 = *(const float4*)(Ap + ((c) + 1) * 32 + 4);                        \
            _Pragma("unroll")                                                      \
            for (int nt = 0; nt < 4; ++nt) {                                       \
                NWH[nt] = WhF[((c) + 1) * 256 + nt * 64 + lane];                   \
                NWM[nt] = WmF[((c) + 1) * 256 + nt * 64 + lane];                   \
            }                                                                      \
        }                                                                          \
        s16x8 ah, am;                                                              \
        decomp8(A0, A1, ah, am);                                                   \
        _Pragma("unroll")                                                          \
        for (int nt = 0; nt < 4; ++nt) {                                           \
            accM[nt] = __builtin_amdgcn_mfma_f32_16x16x32_bf16(ah, WH[nt], accM[nt], 0, 0, 0); \
            accS[nt] = __builtin_amdgcn_mfma_f32_16x16x32_bf16(ah, WM[nt], accS[nt], 0, 0, 0); \
            accS[nt] = __builtin_amdgcn_mfma_f32_16x16x32_bf16(am, WH[nt], accS[nt], 0, 0, 0); \
        }                                                                          \
    }

    for (int c = 0; c < NCH; c += 2) {
        ROUTER_STEP(aA0, aA1, whA, wmA, aB0, aB1, whB, wmB, c);
        ROUTER_STEP(aB0, aB1, whB, wmB, aA0, aA1, whA, wmA, c + 1);
    }
#undef ROUTER_STEP

    // C/D layout: col = lane&15, row = (lane>>4)*4 + reg  [m89-verified]
    #pragma unroll
    for (int nt = 0; nt < 4; ++nt)
        #pragma unroll
        for (int r = 0; r < 4; ++r)
            lg[wv * 16 + (lane >> 4) * 4 + r][nt * 16 + (lane & 15)]
                = accM[nt][r] + 0.00390625f * accS[nt][r];
    __syncthreads();

    // ---- per-row epilogue: 4 waves x 16 rows (proven R1/R3) ----
    float* out_idx   = out;
    float* out_w     = out + 2 * GS;
    float* out_probs = out + 4 * GS + 1;

    const float blane = bias[lane];
    float impL = 0.f, cntL = 0.f;

    for (int rr = 0; rr < 16; ++rr) {
        const int r = (wv << 4) + rr;
        const size_t row = (size_t)row0 + r;
        float v = lg[r][lane] + blane + noise[row * EXP + lane];

        float m = v;
        #pragma unroll
        for (int off = 32; off >= 1; off >>= 1)
            m = fmaxf(m, __shfl_xor(m, off));
        float e = expf(v - m);
        float s = e;
        #pragma unroll
        for (int off = 32; off >= 1; off >>= 1)
            s += __shfl_xor(s, off);
        float p = e / s;

        out_probs[row * EXP + lane] = p;
        impL += p;
        cntL += (p > 0.f) ? 1.f : 0.f;

        float v1 = p; int i1 = lane;
        #pragma unroll
        for (int off = 32; off >= 1; off >>= 1) {
            float ov = __shfl_xor(v1, off);
            int   oi = __shfl_xor(i1, off);
            if (ov > v1 || (ov == v1 && oi < i1)) { v1 = ov; i1 = oi; }
        }
        float v2 = (lane == i1) ? -1.f : p; int i2 = lane;
        #pragma unroll
        for (int off = 32; off >= 1; off >>= 1) {
            float ov = __shfl_xor(v2, off);
            int   oi = __shfl_xor(i2, off);
            if (ov > v2 || (ov == v2 && oi < i2)) { v2 = ov; i2 = oi; }
        }
        if (lane == 0) {
            float denom = v1 + v2 + 1e-9f;
            out_idx[row * 2 + 0] = (float)i1;
            out_idx[row * 2 + 1] = (float)i2;
            out_w[row * 2 + 0] = v1 / denom;
            out_w[row * 2 + 1] = v2 / denom;
        }
    }

    red[wv][lane]     = impL;
    red[4 + wv][lane] = cntL;
    __syncthreads();
    if (tid < EXP) {
        float t1 = red[0][tid] + red[1][tid] + red[2][tid] + red[3][tid];
        float t2 = red[4][tid] + red[5][tid] + red[6][tid] + red[7][tid];
        atomicAdd(&ws[tid], t1);
        atomicAdd(&ws[EXP + tid], t2);
    }
}

__global__ void aux_kernel(const float* __restrict__ ws, float* __restrict__ out)
{
    const int lane = threadIdx.x;  // 64 threads
    float x = ws[lane] * ws[EXP + lane];   // importance * load
    float s = x;
    #pragma unroll
    for (int off = 32; off >= 1; off >>= 1)
        s += __shfl_xor(s, off);
    float mean = s * (1.f / 64.f);
    float d = x - mean;
    float ss = d * d;
    #pragma unroll
    for (int off = 32; off >= 1; off >>= 1)
        ss += __shfl_xor(ss, off);
    if (lane == 0)
        out[4 * GS] = 0.01f * (ss / 63.f);   // unbiased var * 0.01
}

extern "C" void kernel_launch(void* const* d_in, const int* in_sizes, int n_in,
                              void* d_out, int out_size, void* d_ws, size_t ws_size,
                              hipStream_t stream)
{
    const float* tokens = (const float*)d_in[0];
    const float* noise  = (const float*)d_in[1];
    const float* W      = (const float*)d_in[2];
    const float* bias   = (const float*)d_in[3];
    float* out = (float*)d_out;
    float* ws  = (float*)d_ws;

    // ws layout: [0..127] f32 imp/cnt accumulators | WhF (256KB) | WmF (256KB)
    short* WhF = (short*)(ws + 128);
    short* WmF = WhF + (size_t)EXP * HID;

    hipMemsetAsync(ws, 0, 2 * EXP * sizeof(float), stream);
    prep_kernel<<<EXP * HID / 8 / 256, 256, 0, stream>>>(W, WhF, WmF);
    router_kernel<<<GS / BM, 256, 0, stream>>>(tokens, noise, bias,
                                               (const s16x8*)WhF, (const s16x8*)WmF,
                                               out, ws);
    aux_kernel<<<1, 64, 0, stream>>>(ws, out);
}